// Round 1
// baseline (420.162 us; speedup 1.0000x reference)
//
#include <hip/hip_runtime.h>
#include <stdint.h>

typedef unsigned short ushort_t;
typedef __attribute__((ext_vector_type(8))) short short8;
typedef __attribute__((ext_vector_type(4))) float f32x4;
typedef __attribute__((ext_vector_type(4))) ushort_t u16x4;

#define M_ROWS 4096
#define K_DIM  2048
#define N_GATE 8192
#define H_DIM  2048

// ---------- helpers ----------
__device__ __forceinline__ ushort_t f2bf(float f) {
    uint32_t u = __float_as_uint(f);
    uint32_t r = (u + 0x7FFFu + ((u >> 16) & 1u)) >> 16;   // RNE
    return (ushort_t)r;
}
__device__ __forceinline__ float bf2f(ushort_t b) {
    return __uint_as_float(((uint32_t)b) << 16);
}
__device__ __forceinline__ float sigf(float x) {
    return 1.0f / (1.0f + __expf(-x));
}
__device__ __forceinline__ float tanh_fast(float x) {
    float e = __expf(2.0f * x);          // inf for big x -> returns 1; 0 for very neg -> -1
    return 1.0f - 2.0f / (e + 1.0f);
}

// ---------- f32 -> bf16 convert (vectorized) ----------
__global__ void cvt_f32_bf16(const float* __restrict__ in, ushort_t* __restrict__ out, int n) {
    int i = (blockIdx.x * blockDim.x + threadIdx.x) * 4;
    if (i >= n) return;
    float4 v = *(const float4*)(in + i);
    u16x4 o;
    o[0] = f2bf(v.x); o[1] = f2bf(v.y); o[2] = f2bf(v.z); o[3] = f2bf(v.w);
    *(u16x4*)(out + i) = o;
}

// ---------- transpose + convert: W [K][N] f32 -> Wt [N][K] bf16 ----------
__global__ void transpose_cvt(const float* __restrict__ W, ushort_t* __restrict__ Wt,
                              int K, int N) {
    __shared__ float tile[32][33];
    int bn = blockIdx.x * 32;
    int bk = blockIdx.y * 32;
    int tx = threadIdx.x;   // 0..31
    int ty = threadIdx.y;   // 0..7
#pragma unroll
    for (int i = 0; i < 32; i += 8)
        tile[ty + i][tx] = W[(size_t)(bk + ty + i) * N + bn + tx];
    __syncthreads();
#pragma unroll
    for (int i = 0; i < 32; i += 8)
        Wt[(size_t)(bn + ty + i) * K + bk + tx] = f2bf(tile[tx][ty + i]);
}

// ---------- batched GEMM: C[M][N] = A[M][K] @ Bt[N][K]^T  (bf16 in, bf16 out) ----------
// m97 structure: 128x128 tile, BK=64, 4 waves (2x2), 4x4 16x16x32 fragments per wave,
// global_load_lds width-16 staging, 2-barrier K-loop.
#define BM 128
#define BN 128
#define BK 64

__global__ void gemm_bt_bf16(const ushort_t* __restrict__ A0, const ushort_t* __restrict__ B0,
                             ushort_t* __restrict__ C0,
                             const ushort_t* __restrict__ A1, const ushort_t* __restrict__ B1,
                             ushort_t* __restrict__ C1,
                             int M, int N, int K) {
    const ushort_t* A  = blockIdx.z ? A1 : A0;
    const ushort_t* Bt = blockIdx.z ? B1 : B0;
    ushort_t*       C  = blockIdx.z ? C1 : C0;

    __shared__ ushort_t lds[2 * BM * BK];        // As | Bs, 32 KiB
    ushort_t* As = lds;
    ushort_t* Bs = lds + BM * BK;

    const int t    = threadIdx.x;
    const int lane = t & 63;
    const int wid  = t >> 6;
    const int wm   = wid >> 1;                   // 0..1
    const int wn   = wid & 1;                    // 0..1
    const int l15  = lane & 15;
    const int l4   = lane >> 4;

    const int brow = blockIdx.y * BM;
    const int bcol = blockIdx.x * BN;

    // staging map: thread t loads 16B -> LDS byte offset t*16 within each 4KB chunk i
    const int srow = t >> 3;                     // 0..31
    const int scol = (t & 7) * 8;                // element col in tile
    const size_t a_base = (size_t)(brow + srow) * K + scol;
    const size_t b_base = (size_t)(bcol + srow) * K + scol;
    const int lds_woff = wid * 512;              // per-wave uniform element base in 2048-chunk

    f32x4 acc[4][4];
#pragma unroll
    for (int m = 0; m < 4; ++m)
#pragma unroll
        for (int n = 0; n < 4; ++n)
            acc[m][n] = f32x4{0.f, 0.f, 0.f, 0.f};

    for (int kt = 0; kt < K; kt += BK) {
        // ---- stage A,B tiles (each 128x64 bf16 = 16KB = 4 calls x 4KB) ----
#pragma unroll
        for (int i = 0; i < 4; ++i) {
            __builtin_amdgcn_global_load_lds(
                (const __attribute__((address_space(1))) void*)(A + a_base + kt + (size_t)i * 32 * K),
                (__attribute__((address_space(3))) void*)(As + i * 2048 + lds_woff), 16, 0, 0);
            __builtin_amdgcn_global_load_lds(
                (const __attribute__((address_space(1))) void*)(Bt + b_base + kt + (size_t)i * 32 * K),
                (__attribute__((address_space(3))) void*)(Bs + i * 2048 + lds_woff), 16, 0, 0);
        }
        asm volatile("s_waitcnt vmcnt(0)" ::: "memory");
        __syncthreads();

        // ---- compute: 2 k-steps of K=32, 16 MFMA each per wave ----
#pragma unroll
        for (int kk = 0; kk < 2; ++kk) {
            short8 a[4], b[4];
#pragma unroll
            for (int m = 0; m < 4; ++m)
                a[m] = *(const short8*)&As[(wm * 64 + m * 16 + l15) * BK + kk * 32 + l4 * 8];
#pragma unroll
            for (int n = 0; n < 4; ++n)
                b[n] = *(const short8*)&Bs[(wn * 64 + n * 16 + l15) * BK + kk * 32 + l4 * 8];
#pragma unroll
            for (int m = 0; m < 4; ++m)
#pragma unroll
                for (int n = 0; n < 4; ++n)
                    acc[m][n] = __builtin_amdgcn_mfma_f32_16x16x32_bf16(a[m], b[n], acc[m][n], 0, 0, 0);
        }
        __syncthreads();
    }

    // ---- epilogue: C/D layout col=lane&15, row=(lane>>4)*4+r ----
#pragma unroll
    for (int m = 0; m < 4; ++m) {
        int crow0 = brow + wm * 64 + m * 16 + l4 * 4;
#pragma unroll
        for (int n = 0; n < 4; ++n) {
            int ccol = bcol + wn * 64 + n * 16 + l15;
#pragma unroll
            for (int r = 0; r < 4; ++r)
                C[(size_t)(crow0 + r) * N + ccol] = f2bf(acc[m][n][r]);
        }
    }
}

// ---------- block reduction of two sums over 256 threads ----------
__device__ __forceinline__ void block_reduce2(float& a, float& b, float* sred, int t) {
#pragma unroll
    for (int o = 32; o; o >>= 1) {
        a += __shfl_down(a, o);
        b += __shfl_down(b, o);
    }
    __syncthreads();                              // protect sred reuse
    if ((t & 63) == 0) { int w = t >> 6; sred[w] = a; sred[4 + w] = b; }
    __syncthreads();
    a = sred[0] + sred[1] + sred[2] + sred[3];
    b = sred[4] + sred[5] + sred[6] + sred[7];
}

// ---------- fused LN(x-gates) + gate nonlinearities + cell LN + h LN ----------
// one block (256 threads) per batch row
__global__ __launch_bounds__(256) void fuse_ln_lstm(
    const ushort_t* __restrict__ xW, const ushort_t* __restrict__ hW,
    const float* __restrict__ c_prev,
    const float* __restrict__ b_ih, const float* __restrict__ b_hh,
    const float* __restrict__ g_x, const float* __restrict__ beta_x,
    const float* __restrict__ g_c, const float* __restrict__ beta_c,
    const float* __restrict__ g_h, const float* __restrict__ beta_h,
    float* __restrict__ h_out, float* __restrict__ c_out) {

    __shared__ float sgx[N_GATE];     // xW + b_ih  (32 KB)
    __shared__ float scell[H_DIM];    // cell pre-LN (8 KB)
    __shared__ float sot[H_DIM];      // o_t         (8 KB)
    __shared__ float sred[8];

    const int b = blockIdx.x;
    const int t = threadIdx.x;
    const ushort_t* xwr = xW + (size_t)b * N_GATE;
    const ushort_t* hwr = hW + (size_t)b * N_GATE;
    const float*    cpr = c_prev + (size_t)b * H_DIM;

    // ---- phase 1: xW row -> LDS (+bias), LN stats over 8192 ----
    float s = 0.f, q = 0.f;
#pragma unroll
    for (int it = 0; it < 4; ++it) {
        int idx = it * 2048 + t * 8;
        short8 v = *(const short8*)&xwr[idx];
#pragma unroll
        for (int j = 0; j < 8; ++j) {
            float f = bf2f((ushort_t)v[j]) + b_ih[idx + j];
            sgx[idx + j] = f;
            s += f; q += f * f;
        }
    }
    block_reduce2(s, q, sred, t);
    const float inv_g = 1.0f / (float)N_GATE;
    float mu   = s * inv_g;
    float rstd = rsqrtf(q * inv_g - mu * mu + 1e-5f);

    // ---- phase 2: gates, activations, cell; cell LN stats ----
    float cs = 0.f, cq = 0.f;
#pragma unroll
    for (int it = 0; it < 8; ++it) {
        int j = it * 256 + t;
        int ji = j, jf = j + 2048, jg = j + 4096, jo = j + 6144;
        float gi = (sgx[ji] - mu) * rstd * g_x[ji] + beta_x[ji] + bf2f(hwr[ji]) + b_hh[ji];
        float gf = (sgx[jf] - mu) * rstd * g_x[jf] + beta_x[jf] + bf2f(hwr[jf]) + b_hh[jf];
        float gg = (sgx[jg] - mu) * rstd * g_x[jg] + beta_x[jg] + bf2f(hwr[jg]) + b_hh[jg];
        float go = (sgx[jo] - mu) * rstd * g_x[jo] + beta_x[jo] + bf2f(hwr[jo]) + b_hh[jo];
        float i_t = sigf(gi);
        float f_t = sigf(gf);
        float g_t = tanh_fast(gg);
        float o_t = sigf(go);
        float cell = f_t * cpr[j] + i_t * g_t;
        scell[j] = cell;
        sot[j]   = o_t;
        cs += cell; cq += cell * cell;
    }
    block_reduce2(cs, cq, sred, t);
    const float inv_h = 1.0f / (float)H_DIM;
    float muc   = cs * inv_h;
    float rstdc = rsqrtf(cq * inv_h - muc * muc + 1e-5f);

    // ---- phase 3: c_t, then h pre-LN stats ----
    float hs = 0.f, hq = 0.f;
#pragma unroll
    for (int it = 0; it < 8; ++it) {
        int j = it * 256 + t;
        float ct = (scell[j] - muc) * rstdc * g_c[j] + beta_c[j];
        c_out[(size_t)b * H_DIM + j] = ct;
        float hp = sot[j] * tanh_fast(ct);
        sgx[j] = hp;                              // reuse LDS
        hs += hp; hq += hp * hp;
    }
    block_reduce2(hs, hq, sred, t);
    float muh   = hs * inv_h;
    float rstdh = rsqrtf(hq * inv_h - muh * muh + 1e-5f);

#pragma unroll
    for (int it = 0; it < 8; ++it) {
        int j = it * 256 + t;
        h_out[(size_t)b * H_DIM + j] = (sgx[j] - muh) * rstdh * g_h[j] + beta_h[j];
    }
}

// ---------- launch ----------
extern "C" void kernel_launch(void* const* d_in, const int* in_sizes, int n_in,
                              void* d_out, int out_size, void* d_ws, size_t ws_size,
                              hipStream_t stream) {
    const float* x      = (const float*)d_in[0];
    const float* h_prev = (const float*)d_in[1];
    const float* c_prev = (const float*)d_in[2];
    const float* W_ih   = (const float*)d_in[3];
    const float* W_hh   = (const float*)d_in[4];
    const float* b_ih   = (const float*)d_in[5];
    const float* b_hh   = (const float*)d_in[6];
    const float* g_x    = (const float*)d_in[7];
    const float* beta_x = (const float*)d_in[8];
    const float* g_c    = (const float*)d_in[9];
    const float* beta_c = (const float*)d_in[10];
    const float* g_h    = (const float*)d_in[11];
    const float* beta_h = (const float*)d_in[12];

    const int M = M_ROWS, K = K_DIM, N = N_GATE;

    // workspace layout (all bf16/ushort): 224 MB total
    ushort_t* Xb   = (ushort_t*)d_ws;                   // M*K   (16 MB)
    ushort_t* Hb   = Xb   + (size_t)M * K;              // M*K   (16 MB)
    ushort_t* WihT = Hb   + (size_t)M * K;              // N*K   (32 MB)
    ushort_t* WhhT = WihT + (size_t)N * K;              // N*K   (32 MB)
    ushort_t* xWb  = WhhT + (size_t)N * K;              // M*N   (64 MB)
    ushort_t* hWb  = xWb  + (size_t)M * N;              // M*N   (64 MB)

    const int n_xh = M * K;                             // 8,388,608 (divisible by 1024)
    cvt_f32_bf16<<<n_xh / (256 * 4), 256, 0, stream>>>(x,      Xb, n_xh);
    cvt_f32_bf16<<<n_xh / (256 * 4), 256, 0, stream>>>(h_prev, Hb, n_xh);

    transpose_cvt<<<dim3(N / 32, K / 32), dim3(32, 8), 0, stream>>>(W_ih, WihT, K, N);
    transpose_cvt<<<dim3(N / 32, K / 32), dim3(32, 8), 0, stream>>>(W_hh, WhhT, K, N);

    gemm_bt_bf16<<<dim3(N / BN, M / BM, 2), 256, 0, stream>>>(
        Xb, WihT, xWb, Hb, WhhT, hWb, M, N, K);

    float* h_out = (float*)d_out;
    float* c_out = h_out + (size_t)M * H_DIM;
    fuse_ln_lstm<<<M, 256, 0, stream>>>(xWb, hWb, c_prev, b_ih, b_hh,
                                        g_x, beta_x, g_c, beta_c, g_h, beta_h,
                                        h_out, c_out);
}

// Round 2
// 385.619 us; speedup vs baseline: 1.0896x; 1.0896x over previous
//
#include <hip/hip_runtime.h>
#include <stdint.h>

typedef unsigned short ushort_t;
typedef __attribute__((ext_vector_type(8))) short short8;
typedef __attribute__((ext_vector_type(4))) float f32x4;
typedef __attribute__((ext_vector_type(4))) ushort_t u16x4;

#define M_ROWS 4096
#define K_DIM  2048
#define N_GATE 8192
#define H_DIM  2048

// ---------- helpers ----------
__device__ __forceinline__ ushort_t f2bf(float f) {
    uint32_t u = __float_as_uint(f);
    uint32_t r = (u + 0x7FFFu + ((u >> 16) & 1u)) >> 16;   // RNE
    return (ushort_t)r;
}
__device__ __forceinline__ float bf2f(ushort_t b) {
    return __uint_as_float(((uint32_t)b) << 16);
}
__device__ __forceinline__ float sigf(float x) {
    return 1.0f / (1.0f + __expf(-x));
}
__device__ __forceinline__ float tanh_fast(float x) {
    float e = __expf(2.0f * x);
    return 1.0f - 2.0f / (e + 1.0f);
}

// ---------- f32 -> bf16 convert (vectorized) ----------
__global__ void cvt_f32_bf16(const float* __restrict__ in, ushort_t* __restrict__ out, int n) {
    int i = (blockIdx.x * blockDim.x + threadIdx.x) * 4;
    if (i >= n) return;
    float4 v = *(const float4*)(in + i);
    u16x4 o;
    o[0] = f2bf(v.x); o[1] = f2bf(v.y); o[2] = f2bf(v.z); o[3] = f2bf(v.w);
    *(u16x4*)(out + i) = o;
}

// ---------- transpose + convert: W [K][N] f32 -> Wt [N][K] bf16 ----------
__global__ void transpose_cvt(const float* __restrict__ W, ushort_t* __restrict__ Wt,
                              int K, int N) {
    __shared__ float tile[32][33];
    int bn = blockIdx.x * 32;
    int bk = blockIdx.y * 32;
    int tx = threadIdx.x;   // 0..31
    int ty = threadIdx.y;   // 0..7
#pragma unroll
    for (int i = 0; i < 32; i += 8)
        tile[ty + i][tx] = W[(size_t)(bk + ty + i) * N + bn + tx];
    __syncthreads();
#pragma unroll
    for (int i = 0; i < 32; i += 8)
        Wt[(size_t)(bn + ty + i) * K + bk + tx] = f2bf(tile[tx][ty + i]);
}

// ============================================================================
// 256x256 8-phase GEMM (T2 st_16x32 swizzle + T3/T4 counted vmcnt + T5 setprio)
// C[M][N] = A[M][K] @ Bt[N][K]^T, bf16 in, bf16 out. BK=64, 512 thr (2x4 waves).
// Wave wm owns C-rows {wm*64..+63} u {128+wm*64..}, wn owns cols {wn*32..} u
// {128+wn*32..} -> each phase (mh,nh quadrant) reads exactly one A/B half.
// Stage schedule: every half staged >=1 phase after its region's last LDS read.
// ============================================================================
#define TBK 64

__global__ __launch_bounds__(512, 2) void gemm256_8ph(
    const ushort_t* __restrict__ A0, const ushort_t* __restrict__ B0, ushort_t* __restrict__ C0,
    const ushort_t* __restrict__ A1, const ushort_t* __restrict__ B1, ushort_t* __restrict__ C1,
    int M, int N, int K) {
    extern __shared__ char smem[];   // 128 KiB: [buf(2)][A|B][half(2)][128][64] bf16, st_16x32 swizzled
    const ushort_t* A  = blockIdx.z ? A1 : A0;
    const ushort_t* Bt = blockIdx.z ? B1 : B0;
    ushort_t*       C  = blockIdx.z ? C1 : C0;

    const int t    = threadIdx.x;
    const int lane = t & 63, wid = t >> 6;
    const int wm   = wid >> 2, wn = wid & 3;      // 2 x 4 waves
    const int l15  = lane & 15;
    const int l4c  = (lane >> 4) * 16;            // k-byte offset component

    const int brow = blockIdx.y * 256;
    const int bcol = blockIdx.x * 256;

    // staging map: thread t -> linear LDS (row=t>>3, colbytes (t&7)*16), source col pre-swizzled
    const int srow = t >> 3;                                  // 0..63
    const int scol = ((t & 7) * 8) ^ (((t >> 5) & 1) * 16);   // element col (inverse st_16x32)
    const ushort_t* gA = A  + (size_t)(brow + srow) * K + scol;
    const ushort_t* gB = Bt + (size_t)(bcol + srow) * K + scol;
    const int ldsw = wid * 1024;

    // fragment read offsets (bytes within a 16KB half)
    int aR[4], abit[4], bR[2], bbit[2];
#pragma unroll
    for (int fm = 0; fm < 4; ++fm) { int r = wm * 64 + fm * 16 + l15; aR[fm] = r * 128; abit[fm] = ((r >> 2) & 1) << 5; }
#pragma unroll
    for (int fn = 0; fn < 2; ++fn) { int r = wn * 32 + fn * 16 + l15; bR[fn] = r * 128; bbit[fn] = ((r >> 2) & 1) << 5; }

    f32x4 acc[8][4];
#pragma unroll
    for (int i = 0; i < 8; ++i)
#pragma unroll
        for (int j = 0; j < 4; ++j) acc[i][j] = f32x4{0.f, 0.f, 0.f, 0.f};

    short8 a[4][2], b0[2][2], b1[2][2];

#define STAGE_A(tt, h, buf) { _Pragma("unroll") for (int j = 0; j < 2; ++j) \
    __builtin_amdgcn_global_load_lds( \
        (const __attribute__((address_space(1))) void*)(gA + ((size_t)((h) * 128 + j * 64)) * K + (size_t)(tt) * TBK), \
        (__attribute__((address_space(3))) void*)(smem + (buf) * 65536 + (h) * 16384 + j * 8192 + ldsw), 16, 0, 0); }
#define STAGE_B(tt, h, buf) { _Pragma("unroll") for (int j = 0; j < 2; ++j) \
    __builtin_amdgcn_global_load_lds( \
        (const __attribute__((address_space(1))) void*)(gB + ((size_t)((h) * 128 + j * 64)) * K + (size_t)(tt) * TBK), \
        (__attribute__((address_space(3))) void*)(smem + 32768 + (buf) * 65536 + (h) * 16384 + j * 8192 + ldsw), 16, 0, 0); }
#define LDA(mh, buf) { _Pragma("unroll") for (int fm = 0; fm < 4; ++fm) _Pragma("unroll") for (int ks = 0; ks < 2; ++ks) \
    a[fm][ks] = *(const short8*)(smem + (buf) * 65536 + (mh) * 16384 + aR[fm] + ((ks * 64 + l4c) ^ abit[fm])); }
#define LDB(dst, nh, buf) { _Pragma("unroll") for (int fn = 0; fn < 2; ++fn) _Pragma("unroll") for (int ks = 0; ks < 2; ++ks) \
    dst[fn][ks] = *(const short8*)(smem + 32768 + (buf) * 65536 + (nh) * 16384 + bR[fn] + ((ks * 64 + l4c) ^ bbit[fn])); }
#define BARRIER() __builtin_amdgcn_s_barrier()
#define LGKM0()  { asm volatile("s_waitcnt lgkmcnt(0)" ::: "memory"); __builtin_amdgcn_sched_barrier(0); }
#define VM6()    asm volatile("s_waitcnt vmcnt(6)" ::: "memory")
#define MM(mh, nh, bb) { __builtin_amdgcn_s_setprio(1); \
    _Pragma("unroll") for (int ks = 0; ks < 2; ++ks) \
    _Pragma("unroll") for (int fm = 0; fm < 4; ++fm) \
    _Pragma("unroll") for (int fn = 0; fn < 2; ++fn) \
        acc[(mh) * 4 + fm][(nh) * 2 + fn] = __builtin_amdgcn_mfma_f32_16x16x32_bf16( \
            a[fm][ks], bb[fn][ks], acc[(mh) * 4 + fm][(nh) * 2 + fn], 0, 0, 0); \
    __builtin_amdgcn_s_setprio(0); }

    // ---- prologue: tile0 fully (buf0) + tile1 {Ah0,Bh0,Bh1} (buf1): 14 loads/wave ----
    STAGE_A(0, 0, 0); STAGE_B(0, 0, 0); STAGE_B(0, 1, 0); STAGE_A(0, 1, 0);
    STAGE_A(1, 0, 1); STAGE_B(1, 0, 1); STAGE_B(1, 1, 1);
    VM6();                               // oldest 8 = tile0 complete
    BARRIER();

    const int NT = K / TBK;              // 32 (even)
    for (int tt = 0; tt < NT; tt += 2) {
        const int s2 = (tt + 2) & (NT - 1);   // wrapped prefetch (tail refetch is dead data, safe)
        const int s3 = (tt + 3) & (NT - 1);
        // ph1: buf0 (mh0,nh0) — reads Ah0+Bh0; stage (t+1).Ah1 (its region last read prev ph7)
        LDA(0, 0); LDB(b0, 0, 0);
        STAGE_A(tt + 1, 1, 1);
        BARRIER(); LGKM0(); MM(0, 0, b0); BARRIER();
        // ph2: (mh0,nh1) — reads Bh1; stage (t+2).Ah0 (last read ph1)
        LDB(b1, 1, 0);
        STAGE_A(s2, 0, 0);
        BARRIER(); LGKM0(); MM(0, 1, b1); BARRIER();
        // ph3: (mh1,nh0) — reads Ah1; stage (t+2).Bh0 (last read ph1)
        LDA(1, 0);
        STAGE_B(s2, 0, 0);
        BARRIER(); LGKM0(); MM(1, 0, b0); BARRIER();
        // ph4: (mh1,nh1) — regs only; stage (t+2).Bh1 (last read ph2); counted vmcnt
        STAGE_B(s2, 1, 0);
        VM6();
        BARRIER(); LGKM0(); MM(1, 1, b1); BARRIER();
        // ph5: buf1 (mh0,nh0); stage (t+2).Ah1 (last read ph3)
        LDA(0, 1); LDB(b0, 0, 1);
        STAGE_A(s2, 1, 0);
        BARRIER(); LGKM0(); MM(0, 0, b0); BARRIER();
        // ph6: stage (t+3).Ah0 (buf1.Ah0 last read ph5)
        LDB(b1, 1, 1);
        STAGE_A(s3, 0, 1);
        BARRIER(); LGKM0(); MM(0, 1, b1); BARRIER();
        // ph7: stage (t+3).Bh0 (last read ph5)
        LDA(1, 1);
        STAGE_B(s3, 0, 1);
        BARRIER(); LGKM0(); MM(1, 0, b0); BARRIER();
        // ph8: stage (t+3).Bh1 (last read ph6); counted vmcnt
        STAGE_B(s3, 1, 1);
        VM6();
        BARRIER(); LGKM0(); MM(1, 1, b1); BARRIER();
    }

    // ---- epilogue: C/D frag layout col=lane&15, row=(lane>>4)*4+r ----
#pragma unroll
    for (int i = 0; i < 8; ++i) {
        const int mh = i >> 2, fm = i & 3;
        const int row0 = brow + mh * 128 + wm * 64 + fm * 16 + (lane >> 4) * 4;
#pragma unroll
        for (int jn = 0; jn < 4; ++jn) {
            const int nh = jn >> 1, fn = jn & 1;
            const int col = bcol + nh * 128 + wn * 32 + fn * 16 + l15;
#pragma unroll
            for (int r = 0; r < 4; ++r)
                C[(size_t)(row0 + r) * N + col] = f2bf(acc[i][jn][r]);
        }
    }
#undef STAGE_A
#undef STAGE_B
#undef LDA
#undef LDB
#undef BARRIER
#undef LGKM0
#undef VM6
#undef MM
}

// ---------- block reduction of two sums over 256 threads ----------
__device__ __forceinline__ void block_reduce2(float& a, float& b, float* sred, int t) {
#pragma unroll
    for (int o = 32; o; o >>= 1) {
        a += __shfl_down(a, o);
        b += __shfl_down(b, o);
    }
    __syncthreads();
    if ((t & 63) == 0) { int w = t >> 6; sred[w] = a; sred[4 + w] = b; }
    __syncthreads();
    a = sred[0] + sred[1] + sred[2] + sred[3];
    b = sred[4] + sred[5] + sred[6] + sred[7];
}

// ---------- fused LN(x-gates) + gate nonlinearities + cell LN + h LN ----------
__global__ __launch_bounds__(256) void fuse_ln_lstm(
    const ushort_t* __restrict__ xW, const ushort_t* __restrict__ hW,
    const float* __restrict__ c_prev,
    const float* __restrict__ b_ih, const float* __restrict__ b_hh,
    const float* __restrict__ g_x, const float* __restrict__ beta_x,
    const float* __restrict__ g_c, const float* __restrict__ beta_c,
    const float* __restrict__ g_h, const float* __restrict__ beta_h,
    float* __restrict__ h_out, float* __restrict__ c_out) {

    __shared__ float sgx[N_GATE];
    __shared__ float scell[H_DIM];
    __shared__ float sot[H_DIM];
    __shared__ float sred[8];

    const int b = blockIdx.x;
    const int t = threadIdx.x;
    const ushort_t* xwr = xW + (size_t)b * N_GATE;
    const ushort_t* hwr = hW + (size_t)b * N_GATE;
    const float*    cpr = c_prev + (size_t)b * H_DIM;

    float s = 0.f, q = 0.f;
#pragma unroll
    for (int it = 0; it < 4; ++it) {
        int idx = it * 2048 + t * 8;
        short8 v = *(const short8*)&xwr[idx];
#pragma unroll
        for (int j = 0; j < 8; ++j) {
            float f = bf2f((ushort_t)v[j]) + b_ih[idx + j];
            sgx[idx + j] = f;
            s += f; q += f * f;
        }
    }
    block_reduce2(s, q, sred, t);
    const float inv_g = 1.0f / (float)N_GATE;
    float mu   = s * inv_g;
    float rstd = rsqrtf(q * inv_g - mu * mu + 1e-5f);

    float cs = 0.f, cq = 0.f;
#pragma unroll
    for (int it = 0; it < 8; ++it) {
        int j = it * 256 + t;
        int ji = j, jf = j + 2048, jg = j + 4096, jo = j + 6144;
        float gi = (sgx[ji] - mu) * rstd * g_x[ji] + beta_x[ji] + bf2f(hwr[ji]) + b_hh[ji];
        float gf = (sgx[jf] - mu) * rstd * g_x[jf] + beta_x[jf] + bf2f(hwr[jf]) + b_hh[jf];
        float gg = (sgx[jg] - mu) * rstd * g_x[jg] + beta_x[jg] + bf2f(hwr[jg]) + b_hh[jg];
        float go = (sgx[jo] - mu) * rstd * g_x[jo] + beta_x[jo] + bf2f(hwr[jo]) + b_hh[jo];
        float i_t = sigf(gi);
        float f_t = sigf(gf);
        float g_t = tanh_fast(gg);
        float o_t = sigf(go);
        float cell = f_t * cpr[j] + i_t * g_t;
        scell[j] = cell;
        sot[j]   = o_t;
        cs += cell; cq += cell * cell;
    }
    block_reduce2(cs, cq, sred, t);
    const float inv_h = 1.0f / (float)H_DIM;
    float muc   = cs * inv_h;
    float rstdc = rsqrtf(cq * inv_h - muc * muc + 1e-5f);

    float hs = 0.f, hq = 0.f;
#pragma unroll
    for (int it = 0; it < 8; ++it) {
        int j = it * 256 + t;
        float ct = (scell[j] - muc) * rstdc * g_c[j] + beta_c[j];
        c_out[(size_t)b * H_DIM + j] = ct;
        float hp = sot[j] * tanh_fast(ct);
        sgx[j] = hp;
        hs += hp; hq += hp * hp;
    }
    block_reduce2(hs, hq, sred, t);
    float muh   = hs * inv_h;
    float rstdh = rsqrtf(hq * inv_h - muh * muh + 1e-5f);

#pragma unroll
    for (int it = 0; it < 8; ++it) {
        int j = it * 256 + t;
        h_out[(size_t)b * H_DIM + j] = (sgx[j] - muh) * rstdh * g_h[j] + beta_h[j];
    }
}

// ---------- launch ----------
extern "C" void kernel_launch(void* const* d_in, const int* in_sizes, int n_in,
                              void* d_out, int out_size, void* d_ws, size_t ws_size,
                              hipStream_t stream) {
    const float* x      = (const float*)d_in[0];
    const float* h_prev = (const float*)d_in[1];
    const float* c_prev = (const float*)d_in[2];
    const float* W_ih   = (const float*)d_in[3];
    const float* W_hh   = (const float*)d_in[4];
    const float* b_ih   = (const float*)d_in[5];
    const float* b_hh   = (const float*)d_in[6];
    const float* g_x    = (const float*)d_in[7];
    const float* beta_x = (const float*)d_in[8];
    const float* g_c    = (const float*)d_in[9];
    const float* beta_c = (const float*)d_in[10];
    const float* g_h    = (const float*)d_in[11];
    const float* beta_h = (const float*)d_in[12];

    const int M = M_ROWS, K = K_DIM, N = N_GATE;

    ushort_t* Xb   = (ushort_t*)d_ws;
    ushort_t* Hb   = Xb   + (size_t)M * K;
    ushort_t* WihT = Hb   + (size_t)M * K;
    ushort_t* WhhT = WihT + (size_t)N * K;
    ushort_t* xWb  = WhhT + (size_t)N * K;
    ushort_t* hWb  = xWb  + (size_t)M * N;

    const int n_xh = M * K;
    cvt_f32_bf16<<<n_xh / (256 * 4), 256, 0, stream>>>(x,      Xb, n_xh);
    cvt_f32_bf16<<<n_xh / (256 * 4), 256, 0, stream>>>(h_prev, Hb, n_xh);

    transpose_cvt<<<dim3(N / 32, K / 32), dim3(32, 8), 0, stream>>>(W_ih, WihT, K, N);
    transpose_cvt<<<dim3(N / 32, K / 32), dim3(32, 8), 0, stream>>>(W_hh, WhhT, K, N);

    static int lds_attr_set = 0;
    if (!lds_attr_set) {
        (void)hipFuncSetAttribute(reinterpret_cast<const void*>(&gemm256_8ph),
                                  hipFuncAttributeMaxDynamicSharedMemorySize, 131072);
        lds_attr_set = 1;
    }
    gemm256_8ph<<<dim3(N / 256, M / 256, 2), 512, 131072, stream>>>(
        Xb, WihT, xWb, Hb, WhhT, hWb, M, N, K);

    float* h_out = (float*)d_out;
    float* c_out = h_out + (size_t)M * H_DIM;
    fuse_ln_lstm<<<M, 256, 0, stream>>>(xWb, hWb, c_prev, b_ih, b_hh,
                                        g_x, beta_x, g_c, beta_c, g_h, beta_h,
                                        h_out, c_out);
}

// Round 3
// 364.572 us; speedup vs baseline: 1.1525x; 1.0577x over previous
//
#include <hip/hip_runtime.h>
#include <stdint.h>

typedef unsigned short ushort_t;
typedef __attribute__((ext_vector_type(8))) short short8;
typedef __attribute__((ext_vector_type(4))) float f32x4;
typedef __attribute__((ext_vector_type(4))) ushort_t u16x4;

#define M_ROWS 4096
#define K_DIM  2048
#define N_GATE 8192
#define H_DIM  2048

// ---------- helpers ----------
__device__ __forceinline__ ushort_t f2bf(float f) {
    uint32_t u = __float_as_uint(f);
    uint32_t r = (u + 0x7FFFu + ((u >> 16) & 1u)) >> 16;   // RNE
    return (ushort_t)r;
}
__device__ __forceinline__ float bf2f(ushort_t b) {
    return __uint_as_float(((uint32_t)b) << 16);
}
__device__ __forceinline__ float sigf(float x) {
    return 1.0f / (1.0f + __expf(-x));
}
__device__ __forceinline__ float tanh_fast(float x) {
    float e = __expf(2.0f * x);
    return 1.0f - 2.0f / (e + 1.0f);
}

// ---------- f32 -> bf16 convert (vectorized) ----------
__global__ void cvt_f32_bf16(const float* __restrict__ in, ushort_t* __restrict__ out, int n) {
    int i = (blockIdx.x * blockDim.x + threadIdx.x) * 4;
    if (i >= n) return;
    float4 v = *(const float4*)(in + i);
    u16x4 o;
    o[0] = f2bf(v.x); o[1] = f2bf(v.y); o[2] = f2bf(v.z); o[3] = f2bf(v.w);
    *(u16x4*)(out + i) = o;
}

// ---------- transpose + convert: W [K][N] f32 -> Wt [N][K] bf16 ----------
__global__ void transpose_cvt(const float* __restrict__ W, ushort_t* __restrict__ Wt,
                              int K, int N) {
    __shared__ float tile[32][33];
    int bn = blockIdx.x * 32;
    int bk = blockIdx.y * 32;
    int tx = threadIdx.x;   // 0..31
    int ty = threadIdx.y;   // 0..7
#pragma unroll
    for (int i = 0; i < 32; i += 8)
        tile[ty + i][tx] = W[(size_t)(bk + ty + i) * N + bn + tx];
    __syncthreads();
#pragma unroll
    for (int i = 0; i < 32; i += 8)
        Wt[(size_t)(bn + ty + i) * K + bk + tx] = f2bf(tile[tx][ty + i]);
}

// ============================================================================
// 256x256 8-phase GEMM (T2 full 3-bit XOR swizzle + T3/T4 counted vmcnt + T5).
// C[M][N] = A[M][K] @ Bt[N][K]^T, bf16 in, bf16 out. BK=64, 512 thr (2x4 waves).
// Swizzle (G4, 128B-row tile): physical_colbyte = logical_colbyte ^ ((row&7)<<4)
//   - stage: linear LDS dest (gload_lds), source col pre-swizzled (involution)
//   - read : ds_read_b128 at colbyte ^ ((row&7)<<4) -> rows 0-7 hit 8 distinct
//     16B slots (all 32 banks); rows 8-15 alias 2-way (free per m136).
// ============================================================================
#define TBK 64

__global__ __launch_bounds__(512, 2) void gemm256_8ph(
    const ushort_t* __restrict__ A0, const ushort_t* __restrict__ B0, ushort_t* __restrict__ C0,
    const ushort_t* __restrict__ A1, const ushort_t* __restrict__ B1, ushort_t* __restrict__ C1,
    int M, int N, int K) {
    extern __shared__ char smem[];   // 128 KiB: [buf(2)][A|B][half(2)][128][64] bf16, swizzled
    const ushort_t* A  = blockIdx.z ? A1 : A0;
    const ushort_t* Bt = blockIdx.z ? B1 : B0;
    ushort_t*       C  = blockIdx.z ? C1 : C0;

    const int t    = threadIdx.x;
    const int lane = t & 63, wid = t >> 6;
    const int wm   = wid >> 2, wn = wid & 3;      // 2 x 4 waves
    const int l15  = lane & 15;
    const int l4c  = (lane >> 4) * 16;            // k-byte offset component

    const int brow = blockIdx.y * 256;
    const int bcol = blockIdx.x * 256;

    // staging map: thread t -> linear LDS (row=t>>3, colbyte (t&7)*16); global source
    // column carries the inverse swizzle: elem col = ((t&7) ^ ((t>>3)&7)) * 8
    const int srow = t >> 3;                                  // 0..63
    const int scol = (((t & 7) ^ ((t >> 3) & 7)) * 8);        // pre-swizzled source col (elems)
    const ushort_t* gA = A  + (size_t)(brow + srow) * K + scol;
    const ushort_t* gB = Bt + (size_t)(bcol + srow) * K + scol;
    const int ldsw = wid * 1024;

    // fragment read offsets (bytes within a 16KB half)
    int aR[4], abit[4], bR[2], bbit[2];
#pragma unroll
    for (int fm = 0; fm < 4; ++fm) { int r = wm * 64 + fm * 16 + l15; aR[fm] = r * 128; abit[fm] = (r & 7) << 4; }
#pragma unroll
    for (int fn = 0; fn < 2; ++fn) { int r = wn * 32 + fn * 16 + l15; bR[fn] = r * 128; bbit[fn] = (r & 7) << 4; }

    f32x4 acc[8][4];
#pragma unroll
    for (int i = 0; i < 8; ++i)
#pragma unroll
        for (int j = 0; j < 4; ++j) acc[i][j] = f32x4{0.f, 0.f, 0.f, 0.f};

    short8 a[4][2], b0[2][2], b1[2][2];

#define STAGE_A(tt, h, buf) { _Pragma("unroll") for (int j = 0; j < 2; ++j) \
    __builtin_amdgcn_global_load_lds( \
        (const __attribute__((address_space(1))) void*)(gA + ((size_t)((h) * 128 + j * 64)) * K + (size_t)(tt) * TBK), \
        (__attribute__((address_space(3))) void*)(smem + (buf) * 65536 + (h) * 16384 + j * 8192 + ldsw), 16, 0, 0); }
#define STAGE_B(tt, h, buf) { _Pragma("unroll") for (int j = 0; j < 2; ++j) \
    __builtin_amdgcn_global_load_lds( \
        (const __attribute__((address_space(1))) void*)(gB + ((size_t)((h) * 128 + j * 64)) * K + (size_t)(tt) * TBK), \
        (__attribute__((address_space(3))) void*)(smem + 32768 + (buf) * 65536 + (h) * 16384 + j * 8192 + ldsw), 16, 0, 0); }
#define LDA(mh, buf) { _Pragma("unroll") for (int fm = 0; fm < 4; ++fm) _Pragma("unroll") for (int ks = 0; ks < 2; ++ks) \
    a[fm][ks] = *(const short8*)(smem + (buf) * 65536 + (mh) * 16384 + aR[fm] + ((ks * 64 + l4c) ^ abit[fm])); }
#define LDB(dst, nh, buf) { _Pragma("unroll") for (int fn = 0; fn < 2; ++fn) _Pragma("unroll") for (int ks = 0; ks < 2; ++ks) \
    dst[fn][ks] = *(const short8*)(smem + 32768 + (buf) * 65536 + (nh) * 16384 + bR[fn] + ((ks * 64 + l4c) ^ bbit[fn])); }
#define BARRIER() __builtin_amdgcn_s_barrier()
#define LGKM0()  { asm volatile("s_waitcnt lgkmcnt(0)" ::: "memory"); __builtin_amdgcn_sched_barrier(0); }
#define VM6()    asm volatile("s_waitcnt vmcnt(6)" ::: "memory")
#define MM(mh, nh, bb) { __builtin_amdgcn_s_setprio(1); \
    _Pragma("unroll") for (int ks = 0; ks < 2; ++ks) \
    _Pragma("unroll") for (int fm = 0; fm < 4; ++fm) \
    _Pragma("unroll") for (int fn = 0; fn < 2; ++fn) \
        acc[(mh) * 4 + fm][(nh) * 2 + fn] = __builtin_amdgcn_mfma_f32_16x16x32_bf16( \
            a[fm][ks], bb[fn][ks], acc[(mh) * 4 + fm][(nh) * 2 + fn], 0, 0, 0); \
    __builtin_amdgcn_s_setprio(0); }

    // ---- prologue: tile0 fully (buf0) + tile1 {Ah0,Bh0,Bh1} (buf1): 14 loads/wave ----
    STAGE_A(0, 0, 0); STAGE_B(0, 0, 0); STAGE_B(0, 1, 0); STAGE_A(0, 1, 0);
    STAGE_A(1, 0, 1); STAGE_B(1, 0, 1); STAGE_B(1, 1, 1);
    VM6();                               // oldest 8 = tile0 complete
    BARRIER();

    const int NT = K / TBK;              // 32 (even)
    for (int tt = 0; tt < NT; tt += 2) {
        const int s2 = (tt + 2) & (NT - 1);   // wrapped prefetch (tail refetch is dead data, safe)
        const int s3 = (tt + 3) & (NT - 1);
        // ph1: buf0 (mh0,nh0) — reads Ah0+Bh0; stage (t+1).Ah1 (its region last read prev ph7)
        LDA(0, 0); LDB(b0, 0, 0);
        STAGE_A(tt + 1, 1, 1);
        BARRIER(); LGKM0(); MM(0, 0, b0); BARRIER();
        // ph2: (mh0,nh1) — reads Bh1; stage (t+2).Ah0 (last read ph1)
        LDB(b1, 1, 0);
        STAGE_A(s2, 0, 0);
        BARRIER(); LGKM0(); MM(0, 1, b1); BARRIER();
        // ph3: (mh1,nh0) — reads Ah1; stage (t+2).Bh0 (last read ph1)
        LDA(1, 0);
        STAGE_B(s2, 0, 0);
        BARRIER(); LGKM0(); MM(1, 0, b0); BARRIER();
        // ph4: (mh1,nh1) — regs only; stage (t+2).Bh1 (last read ph2); counted vmcnt
        STAGE_B(s2, 1, 0);
        VM6();
        BARRIER(); LGKM0(); MM(1, 1, b1); BARRIER();
        // ph5: buf1 (mh0,nh0); stage (t+2).Ah1 (last read ph3)
        LDA(0, 1); LDB(b0, 0, 1);
        STAGE_A(s2, 1, 0);
        BARRIER(); LGKM0(); MM(0, 0, b0); BARRIER();
        // ph6: stage (t+3).Ah0 (buf1.Ah0 last read ph5)
        LDB(b1, 1, 1);
        STAGE_A(s3, 0, 1);
        BARRIER(); LGKM0(); MM(0, 1, b1); BARRIER();
        // ph7: stage (t+3).Bh0 (last read ph5)
        LDA(1, 1);
        STAGE_B(s3, 0, 1);
        BARRIER(); LGKM0(); MM(1, 0, b0); BARRIER();
        // ph8: stage (t+3).Bh1 (last read ph6); counted vmcnt
        STAGE_B(s3, 1, 1);
        VM6();
        BARRIER(); LGKM0(); MM(1, 1, b1); BARRIER();
    }

    // ---- epilogue: C/D frag layout col=lane&15, row=(lane>>4)*4+r ----
#pragma unroll
    for (int i = 0; i < 8; ++i) {
        const int mh = i >> 2, fm = i & 3;
        const int row0 = brow + mh * 128 + wm * 64 + fm * 16 + (lane >> 4) * 4;
#pragma unroll
        for (int jn = 0; jn < 4; ++jn) {
            const int nh = jn >> 1, fn = jn & 1;
            const int col = bcol + nh * 128 + wn * 32 + fn * 16 + l15;
#pragma unroll
            for (int r = 0; r < 4; ++r)
                C[(size_t)(row0 + r) * N + col] = f2bf(acc[i][jn][r]);
        }
    }
#undef STAGE_A
#undef STAGE_B
#undef LDA
#undef LDB
#undef BARRIER
#undef LGKM0
#undef VM6
#undef MM
}

// ---------- block reduction of two sums over 256 threads ----------
__device__ __forceinline__ void block_reduce2(float& a, float& b, float* sred, int t) {
#pragma unroll
    for (int o = 32; o; o >>= 1) {
        a += __shfl_down(a, o);
        b += __shfl_down(b, o);
    }
    __syncthreads();
    if ((t & 63) == 0) { int w = t >> 6; sred[w] = a; sred[4 + w] = b; }
    __syncthreads();
    a = sred[0] + sred[1] + sred[2] + sred[3];
    b = sred[4] + sred[5] + sred[6] + sred[7];
}

// ---------- fused LN(x-gates) + gate nonlinearities + cell LN + h LN ----------
__global__ __launch_bounds__(256) void fuse_ln_lstm(
    const ushort_t* __restrict__ xW, const ushort_t* __restrict__ hW,
    const float* __restrict__ c_prev,
    const float* __restrict__ b_ih, const float* __restrict__ b_hh,
    const float* __restrict__ g_x, const float* __restrict__ beta_x,
    const float* __restrict__ g_c, const float* __restrict__ beta_c,
    const float* __restrict__ g_h, const float* __restrict__ beta_h,
    float* __restrict__ h_out, float* __restrict__ c_out) {

    __shared__ float sgx[N_GATE];
    __shared__ float scell[H_DIM];
    __shared__ float sot[H_DIM];
    __shared__ float sred[8];

    const int b = blockIdx.x;
    const int t = threadIdx.x;
    const ushort_t* xwr = xW + (size_t)b * N_GATE;
    const ushort_t* hwr = hW + (size_t)b * N_GATE;
    const float*    cpr = c_prev + (size_t)b * H_DIM;

    float s = 0.f, q = 0.f;
#pragma unroll
    for (int it = 0; it < 4; ++it) {
        int idx = it * 2048 + t * 8;
        short8 v = *(const short8*)&xwr[idx];
#pragma unroll
        for (int j = 0; j < 8; ++j) {
            float f = bf2f((ushort_t)v[j]) + b_ih[idx + j];
            sgx[idx + j] = f;
            s += f; q += f * f;
        }
    }
    block_reduce2(s, q, sred, t);
    const float inv_g = 1.0f / (float)N_GATE;
    float mu   = s * inv_g;
    float rstd = rsqrtf(q * inv_g - mu * mu + 1e-5f);

    float cs = 0.f, cq = 0.f;
#pragma unroll
    for (int it = 0; it < 8; ++it) {
        int j = it * 256 + t;
        int ji = j, jf = j + 2048, jg = j + 4096, jo = j + 6144;
        float gi = (sgx[ji] - mu) * rstd * g_x[ji] + beta_x[ji] + bf2f(hwr[ji]) + b_hh[ji];
        float gf = (sgx[jf] - mu) * rstd * g_x[jf] + beta_x[jf] + bf2f(hwr[jf]) + b_hh[jf];
        float gg = (sgx[jg] - mu) * rstd * g_x[jg] + beta_x[jg] + bf2f(hwr[jg]) + b_hh[jg];
        float go = (sgx[jo] - mu) * rstd * g_x[jo] + beta_x[jo] + bf2f(hwr[jo]) + b_hh[jo];
        float i_t = sigf(gi);
        float f_t = sigf(gf);
        float g_t = tanh_fast(gg);
        float o_t = sigf(go);
        float cell = f_t * cpr[j] + i_t * g_t;
        scell[j] = cell;
        sot[j]   = o_t;
        cs += cell; cq += cell * cell;
    }
    block_reduce2(cs, cq, sred, t);
    const float inv_h = 1.0f / (float)H_DIM;
    float muc   = cs * inv_h;
    float rstdc = rsqrtf(cq * inv_h - muc * muc + 1e-5f);

    float hs = 0.f, hq = 0.f;
#pragma unroll
    for (int it = 0; it < 8; ++it) {
        int j = it * 256 + t;
        float ct = (scell[j] - muc) * rstdc * g_c[j] + beta_c[j];
        c_out[(size_t)b * H_DIM + j] = ct;
        float hp = sot[j] * tanh_fast(ct);
        sgx[j] = hp;
        hs += hp; hq += hp * hp;
    }
    block_reduce2(hs, hq, sred, t);
    float muh   = hs * inv_h;
    float rstdh = rsqrtf(hq * inv_h - muh * muh + 1e-5f);

#pragma unroll
    for (int it = 0; it < 8; ++it) {
        int j = it * 256 + t;
        h_out[(size_t)b * H_DIM + j] = (sgx[j] - muh) * rstdh * g_h[j] + beta_h[j];
    }
}

// ---------- launch ----------
extern "C" void kernel_launch(void* const* d_in, const int* in_sizes, int n_in,
                              void* d_out, int out_size, void* d_ws, size_t ws_size,
                              hipStream_t stream) {
    const float* x      = (const float*)d_in[0];
    const float* h_prev = (const float*)d_in[1];
    const float* c_prev = (const float*)d_in[2];
    const float* W_ih   = (const float*)d_in[3];
    const float* W_hh   = (const float*)d_in[4];
    const float* b_ih   = (const float*)d_in[5];
    const float* b_hh   = (const float*)d_in[6];
    const float* g_x    = (const float*)d_in[7];
    const float* beta_x = (const float*)d_in[8];
    const float* g_c    = (const float*)d_in[9];
    const float* beta_c = (const float*)d_in[10];
    const float* g_h    = (const float*)d_in[11];
    const float* beta_h = (const float*)d_in[12];

    const int M = M_ROWS, K = K_DIM, N = N_GATE;

    ushort_t* Xb   = (ushort_t*)d_ws;
    ushort_t* Hb   = Xb   + (size_t)M * K;
    ushort_t* WihT = Hb   + (size_t)M * K;
    ushort_t* WhhT = WihT + (size_t)N * K;
    ushort_t* xWb  = WhhT + (size_t)N * K;
    ushort_t* hWb  = xWb  + (size_t)M * N;

    const int n_xh = M * K;
    cvt_f32_bf16<<<n_xh / (256 * 4), 256, 0, stream>>>(x,      Xb, n_xh);
    cvt_f32_bf16<<<n_xh / (256 * 4), 256, 0, stream>>>(h_prev, Hb, n_xh);

    transpose_cvt<<<dim3(N / 32, K / 32), dim3(32, 8), 0, stream>>>(W_ih, WihT, K, N);
    transpose_cvt<<<dim3(N / 32, K / 32), dim3(32, 8), 0, stream>>>(W_hh, WhhT, K, N);

    static int lds_attr_set = 0;
    if (!lds_attr_set) {
        (void)hipFuncSetAttribute(reinterpret_cast<const void*>(&gemm256_8ph),
                                  hipFuncAttributeMaxDynamicSharedMemorySize, 131072);
        lds_attr_set = 1;
    }
    gemm256_8ph<<<dim3(N / 256, M / 256, 2), 512, 131072, stream>>>(
        Xb, WihT, xWb, Hb, WhhT, hWb, M, N, K);

    float* h_out = (float*)d_out;
    float* c_out = h_out + (size_t)M * H_DIM;
    fuse_ln_lstm<<<M, 256, 0, stream>>>(xWb, hWb, c_prev, b_ih, b_hh,
                                        g_x, beta_x, g_c, beta_c, g_h, beta_h,
                                        h_out, c_out);
}